// Round 1
// baseline (15751.941 us; speedup 1.0000x reference)
//
#include <hip/hip_runtime.h>
#include <math.h>

#define L 12
#define H 768
#define NH 12
#define DH 64
#define FF 3072
#define B 32
#define R 29
#define D 14
#define E 15
#define RK 8
#define S 30
#define H2 384
#define T (B*S)
#define SCALING 2.0f

__device__ __forceinline__ float gelu_f(float x) {
    return 0.5f * x * (1.0f + erff(x * 0.70710678118654752f));
}

// block reduce over 256 threads (4 waves of 64)
__device__ __forceinline__ float block_sum256(float v, float* red) {
    int tid = threadIdx.x;
    #pragma unroll
    for (int off = 32; off > 0; off >>= 1) v += __shfl_down(v, off, 64);
    if ((tid & 63) == 0) red[tid >> 6] = v;
    __syncthreads();
    float s = red[0] + red[1] + red[2] + red[3];
    __syncthreads();
    return s;
}

__global__ void init_hs(const float* __restrict__ region, const float* __restrict__ cls,
                        float* __restrict__ hs) {
    int idx = blockIdx.x * blockDim.x + threadIdx.x;
    if (idx >= T * H) return;
    int h = idx % H;
    int t = idx / H;
    int s = t % S;
    int b = t / S;
    hs[idx] = (s == 0) ? cls[h] : region[((size_t)b * R + (s - 1)) * H + h];
}

// LayerNorm: one block per token, H=768=3*256
__global__ __launch_bounds__(256) void ln_kernel(const float* __restrict__ x,
                                                 const float* __restrict__ w,
                                                 const float* __restrict__ b,
                                                 float* __restrict__ out, float eps) {
    __shared__ float red[4];
    int t = blockIdx.x;
    const float* xp = x + (size_t)t * H;
    float vals[3];
    float lsum = 0.f;
    #pragma unroll
    for (int i = 0; i < 3; i++) { vals[i] = xp[threadIdx.x + i * 256]; lsum += vals[i]; }
    float mean = block_sum256(lsum, red) * (1.0f / H);
    float lsq = 0.f;
    #pragma unroll
    for (int i = 0; i < 3; i++) { float d = vals[i] - mean; lsq += d * d; }
    float var = block_sum256(lsq, red) * (1.0f / H);
    float rstd = rsqrtf(var + eps);
    #pragma unroll
    for (int i = 0; i < 3; i++) {
        int h = threadIdx.x + i * 256;
        out[(size_t)t * H + h] = (vals[i] - mean) * rstd * w[h] + b[h];
    }
}

// C[m,n] = act( sum_k A[m,k]*W[n,k] + bias[n] );  if Cres: Cres = C + resid
__global__ __launch_bounds__(256) void gemm_kernel(
    const float* __restrict__ A, const float* __restrict__ W,
    const float* __restrict__ bias, const float* __restrict__ resid,
    float* __restrict__ C, float* __restrict__ Cres,
    int M, int N, int K, int act)
{
    __shared__ float As[64][17];
    __shared__ float Ws[64][17];
    int tid = threadIdx.x;
    int tx = tid & 15, ty = tid >> 4;
    int m0 = blockIdx.y * 64, n0 = blockIdx.x * 64;
    float acc[4][4] = {};
    for (int k0 = 0; k0 < K; k0 += 16) {
        #pragma unroll
        for (int t = 0; t < 4; ++t) {
            int e = tid + t * 256;
            int r = e >> 4, c = e & 15;
            int m = m0 + r;
            As[r][c] = (m < M) ? A[(size_t)m * K + k0 + c] : 0.f;
            int n = n0 + r;
            Ws[r][c] = (n < N) ? W[(size_t)n * K + k0 + c] : 0.f;
        }
        __syncthreads();
        #pragma unroll
        for (int kk = 0; kk < 16; ++kk) {
            float a[4], w[4];
            #pragma unroll
            for (int i = 0; i < 4; i++) a[i] = As[ty * 4 + i][kk];
            #pragma unroll
            for (int j = 0; j < 4; j++) w[j] = Ws[tx * 4 + j][kk];
            #pragma unroll
            for (int i = 0; i < 4; i++)
                #pragma unroll
                for (int j = 0; j < 4; j++)
                    acc[i][j] = fmaf(a[i], w[j], acc[i][j]);
        }
        __syncthreads();
    }
    #pragma unroll
    for (int i = 0; i < 4; i++) {
        int m = m0 + ty * 4 + i;
        if (m >= M) continue;
        #pragma unroll
        for (int j = 0; j < 4; j++) {
            int n = n0 + tx * 4 + j;
            if (n >= N) continue;
            float v = acc[i][j] + (bias ? bias[n] : 0.f);
            if (act == 1) v = gelu_f(v);
            size_t o = (size_t)m * N + n;
            C[o] = v;
            if (Cres) Cres[o] = v + resid[o];
        }
    }
}

// fused attention: one block per (b, head); qkv stored (token, 3H)
__global__ __launch_bounds__(256) void attn_kernel(const float* __restrict__ qkv,
                                                   float* __restrict__ ctx) {
    int b = blockIdx.x / NH, nh = blockIdx.x % NH;
    __shared__ float qs[S * DH], ks[S * DH], vs[S * DH];
    __shared__ float sc[S][S + 1];
    int tid = threadIdx.x;
    for (int e = tid; e < S * DH; e += 256) {
        int s = e / DH, d = e % DH;
        size_t base = (size_t)(b * S + s) * (3 * H) + nh * DH + d;
        qs[e] = qkv[base];
        ks[e] = qkv[base + H];
        vs[e] = qkv[base + 2 * H];
    }
    __syncthreads();
    for (int e = tid; e < S * S; e += 256) {
        int qi = e / S, kj = e % S;
        float acc = 0.f;
        #pragma unroll
        for (int d = 0; d < DH; d++) acc += qs[qi * DH + d] * ks[kj * DH + d];
        sc[qi][kj] = acc * 0.125f;  // 1/sqrt(64)
    }
    __syncthreads();
    if (tid < S) {
        float mx = -1e30f;
        for (int k = 0; k < S; k++) mx = fmaxf(mx, sc[tid][k]);
        float sum = 0.f;
        for (int k = 0; k < S; k++) { float ex = __expf(sc[tid][k] - mx); sc[tid][k] = ex; sum += ex; }
        float inv = 1.0f / sum;
        for (int k = 0; k < S; k++) sc[tid][k] *= inv;
    }
    __syncthreads();
    for (int e = tid; e < S * DH; e += 256) {
        int s = e / DH, d = e % DH;
        float acc = 0.f;
        for (int k = 0; k < S; k++) acc += sc[s][k] * vs[k * DH + d];
        ctx[(size_t)(b * S + s) * H + nh * DH + d] = acc;
    }
}

// pooled[b,d,h] = sum_r attn_out[b,1+r,h]*mask[r,d] / max(cnt[d],1)
__global__ __launch_bounds__(256) void pool_kernel(const float* __restrict__ attn_out,
                                                   const float* __restrict__ mask,
                                                   float* __restrict__ pooled) {
    int b = blockIdx.x / D, d = blockIdx.x % D;
    float cnt = 0.f;
    for (int r = 0; r < R; r++) cnt += mask[r * D + d];
    float inv = 1.0f / fmaxf(cnt, 1.0f);
    for (int h = threadIdx.x; h < H; h += 256) {
        float acc = 0.f;
        for (int r = 0; r < R; r++) {
            float mv = mask[r * D + d];
            if (mv != 0.f) acc += attn_out[(size_t)(b * S + 1 + r) * H + h] * mv;
        }
        pooled[(size_t)(b * D + d) * H + h] = acc * inv;
    }
}

// cls head: block per (b,d) -> active_dis[b,d] in {0,1}
__global__ __launch_bounds__(256) void cls_kernel(
    const float* __restrict__ pooled, const float* __restrict__ w1,
    const float* __restrict__ b1, const float* __restrict__ lnw,
    const float* __restrict__ lnb, const float* __restrict__ w2,
    const float* __restrict__ b2, const float* __restrict__ mask,
    float* __restrict__ act_dis)
{
    int b = blockIdx.x / D, d = blockIdx.x % D;
    __shared__ float h1[H2];
    __shared__ float red[4];
    const float* pp = pooled + (size_t)(b * D + d) * H;
    for (int k = threadIdx.x; k < H2; k += 256) {
        const float* wp = w1 + ((size_t)d * H2 + k) * H;
        float acc = 0.f;
        for (int h = 0; h < H; h++) acc += pp[h] * wp[h];
        h1[k] = acc + b1[d * H2 + k];
    }
    __syncthreads();
    float ls = 0.f;
    for (int k = threadIdx.x; k < H2; k += 256) ls += h1[k];
    float mean = block_sum256(ls, red) * (1.0f / H2);
    float lq = 0.f;
    for (int k = threadIdx.x; k < H2; k += 256) { float dv = h1[k] - mean; lq += dv * dv; }
    float var = block_sum256(lq, red) * (1.0f / H2);
    float rstd = rsqrtf(var + 1e-5f);
    float lp = 0.f;
    for (int k = threadIdx.x; k < H2; k += 256) {
        float g = gelu_f((h1[k] - mean) * rstd * lnw[d * H2 + k] + lnb[d * H2 + k]);
        lp += g * w2[d * H2 + k];
    }
    float pred = block_sum256(lp, red) + b2[d];
    if (threadIdx.x == 0) {
        float cnt = 0.f;
        for (int r = 0; r < R; r++) cnt += mask[r * D + d];
        // sigmoid(pred) > 0.5  <=>  pred > 0 ; preds forced 0 when cnt==0 -> inactive
        act_dis[b * D + d] = (cnt > 0.f && pred > 0.f) ? 1.0f : 0.0f;
    }
}

// expert mixture weights w[b,s,e]
__global__ void w_kernel(const float* __restrict__ act_dis, const float* __restrict__ mask,
                         float* __restrict__ wbuf) {
    int t = blockIdx.x * blockDim.x + threadIdx.x;
    if (t >= T) return;
    int b = t / S, s = t % S;
    float a[E];
    float sum = 0.f;
    for (int d = 0; d < D; d++) {
        float v = 0.f;
        if (s > 0 && mask[(s - 1) * D + d] > 0.f) v = act_dis[b * D + d];
        a[d] = v; sum += v;
    }
    a[D] = 1.0f; sum += 1.0f;
    float inv = 1.0f / fmaxf(sum, 1.0f);
    for (int e = 0; e < E; e++) wbuf[t * E + e] = a[e] * inv;
}

// M[e,r,r2] = sum_f B_up[e,f,r2] * A_down[e,r,f]  (per even layer)
__global__ __launch_bounds__(256) void m_kernel(const float* __restrict__ Bup,
                                                const float* __restrict__ Adn,
                                                float* __restrict__ Mbuf) {
    __shared__ float red[4];
    int id = blockIdx.x;
    int e = id / (RK * RK);
    int r = (id / RK) % RK;
    int r2 = id % RK;
    float acc = 0.f;
    for (int f = threadIdx.x; f < FF; f += 256)
        acc += Bup[((size_t)e * FF + f) * RK + r2] * Adn[((size_t)e * RK + r) * FF + f];
    float s = block_sum256(acc, red);
    if (threadIdx.x == 0) Mbuf[id] = s;
}

// per-token expert combine: a_dn -> lora_dn -> LN-noaffine -> weighted sum -> +res1
__global__ __launch_bounds__(256) void expert_kernel(
    const float* __restrict__ base_out, const float* __restrict__ aup,
    const float* __restrict__ dn0, const float* __restrict__ Mbuf,
    const float* __restrict__ wbuf, const float* __restrict__ Bdn,
    const float* __restrict__ res1, float* __restrict__ hs)
{
    int t = blockIdx.x;
    __shared__ float bo[H], vtmp[H], fin[H];
    __shared__ float Ms[E * RK * RK];
    __shared__ float aups[E * RK], dn0s[E * RK], adn[RK], ws_[E];
    __shared__ float red[4];
    int tid = threadIdx.x;
    for (int h = tid; h < H; h += 256) { bo[h] = base_out[(size_t)t * H + h]; fin[h] = 0.f; }
    for (int i = tid; i < E * RK * RK; i += 256) Ms[i] = Mbuf[i];
    for (int i = tid; i < E * RK; i += 256) {
        aups[i] = aup[(size_t)t * E * RK + i];
        dn0s[i] = dn0[(size_t)t * E * RK + i];
    }
    if (tid < E) ws_[tid] = wbuf[t * E + tid];
    __syncthreads();
    for (int e = 0; e < E; e++) {
        float we = ws_[e];
        if (we == 0.f) continue;  // uniform across block
        if (tid < RK) {
            float acc = dn0s[e * RK + tid];
            #pragma unroll
            for (int r2 = 0; r2 < RK; r2++)
                acc += SCALING * aups[e * RK + r2] * Ms[(e * RK + tid) * RK + r2];
            adn[tid] = acc;
        }
        __syncthreads();
        float lsum = 0.f;
        for (int h = tid; h < H; h += 256) {
            const float* bp = Bdn + ((size_t)e * H + h) * RK;
            float ld = 0.f;
            #pragma unroll
            for (int r = 0; r < RK; r++) ld += adn[r] * bp[r];
            float v = bo[h] + SCALING * ld;
            vtmp[h] = v;
            lsum += v;
        }
        float mean = block_sum256(lsum, red) * (1.0f / H);
        float lq = 0.f;
        for (int h = tid; h < H; h += 256) { float dv = vtmp[h] - mean; lq += dv * dv; }
        float var = block_sum256(lq, red) * (1.0f / H);
        float rstd = rsqrtf(var + 1e-5f);
        for (int h = tid; h < H; h += 256) fin[h] += we * (vtmp[h] - mean) * rstd;
        __syncthreads();
    }
    for (int h = tid; h < H; h += 256)
        hs[(size_t)t * H + h] = fin[h] + res1[(size_t)t * H + h];
}

extern "C" void kernel_launch(void* const* d_in, const int* in_sizes, int n_in,
                              void* d_out, int out_size, void* d_ws, size_t ws_size,
                              hipStream_t stream) {
    (void)in_sizes; (void)n_in; (void)out_size; (void)ws_size;
    const float* region = (const float*)d_in[0];
    const float* mask   = (const float*)d_in[1];
    const float* cls    = (const float*)d_in[2];
    const float* ln1w   = (const float*)d_in[3];
    const float* ln1b   = (const float*)d_in[4];
    const float* qkvw   = (const float*)d_in[5];
    const float* qkvb   = (const float*)d_in[6];
    const float* aow    = (const float*)d_in[7];
    const float* aob    = (const float*)d_in[8];
    const float* ln2w   = (const float*)d_in[9];
    const float* ln2b   = (const float*)d_in[10];
    const float* fw1    = (const float*)d_in[11];
    const float* fb1    = (const float*)d_in[12];
    const float* fw2    = (const float*)d_in[13];
    const float* fb2    = (const float*)d_in[14];
    const float* cw1    = (const float*)d_in[15];
    const float* cb1    = (const float*)d_in[16];
    const float* clnw   = (const float*)d_in[17];
    const float* clnb   = (const float*)d_in[18];
    const float* cw2    = (const float*)d_in[19];
    const float* cb2    = (const float*)d_in[20];
    const float* lAu    = (const float*)d_in[21];
    const float* lBu    = (const float*)d_in[22];
    const float* lAd    = (const float*)d_in[23];
    const float* lBd    = (const float*)d_in[24];
    const float* flnw   = (const float*)d_in[25];
    const float* flnb   = (const float*)d_in[26];

    float* p = (float*)d_ws;
    float* hs   = p; p += (size_t)T * H;
    float* xln  = p; p += (size_t)T * H;       // also reused as ctx
    float* qkv  = p; p += (size_t)T * 3 * H;
    float* aout = p; p += (size_t)T * H;
    float* res1 = p; p += (size_t)T * H;
    float* y    = p; p += (size_t)T * H;
    float* bh   = p; p += (size_t)T * FF;
    float* bo   = p; p += (size_t)T * H;
    float* aup  = p; p += (size_t)T * E * RK;
    float* dn0  = p; p += (size_t)T * E * RK;
    float* Mbuf = p; p += E * RK * RK;
    float* adis = p; p += B * D;
    float* wb   = p; p += (size_t)T * E;
    float* pooled = p; p += (size_t)B * D * H;
    float* ctx  = xln;  // xln dead after qkv gemm

    init_hs<<<(T * H + 255) / 256, 256, 0, stream>>>(region, cls, hs);

    for (int i = 0; i < L; i++) {
        ln_kernel<<<T, 256, 0, stream>>>(hs, ln1w + i * H, ln1b + i * H, xln, 1e-12f);
        dim3 g1(3 * H / 64, T / 64);
        gemm_kernel<<<g1, 256, 0, stream>>>(xln, qkvw + (size_t)i * 3 * H * H, qkvb + i * 3 * H,
                                            nullptr, qkv, nullptr, T, 3 * H, H, 0);
        attn_kernel<<<B * NH, 256, 0, stream>>>(qkv, ctx);
        dim3 g2(H / 64, T / 64);
        gemm_kernel<<<g2, 256, 0, stream>>>(ctx, aow + (size_t)i * H * H, aob + i * H,
                                            hs, aout, res1, T, H, H, 0);
        ln_kernel<<<T, 256, 0, stream>>>(res1, ln2w + i * H, ln2b + i * H, y, 1e-12f);
        dim3 gf1(FF / 64, T / 64);
        gemm_kernel<<<gf1, 256, 0, stream>>>(y, fw1 + (size_t)i * FF * H, fb1 + i * FF,
                                             nullptr, bh, nullptr, T, FF, H, 1);
        if (i % 2 == 1) {
            dim3 gf2(H / 64, T / 64);
            gemm_kernel<<<gf2, 256, 0, stream>>>(bh, fw2 + (size_t)i * H * FF, fb2 + i * H,
                                                 res1, bo, hs, T, H, FF, 0);
        } else {
            int j = i / 2;
            pool_kernel<<<B * D, 256, 0, stream>>>(aout, mask, pooled);
            cls_kernel<<<B * D, 256, 0, stream>>>(pooled, cw1 + (size_t)j * D * H2 * H,
                cb1 + (size_t)j * D * H2, clnw + (size_t)j * D * H2, clnb + (size_t)j * D * H2,
                cw2 + (size_t)j * D * H2, cb2 + (size_t)j * D, mask, adis);
            w_kernel<<<(T + 255) / 256, 256, 0, stream>>>(adis, mask, wb);
            m_kernel<<<E * RK * RK, 256, 0, stream>>>(lBu + (size_t)j * E * FF * RK,
                                                      lAd + (size_t)j * E * RK * FF, Mbuf);
            dim3 ga((E * RK + 63) / 64, T / 64);
            gemm_kernel<<<ga, 256, 0, stream>>>(y, lAu + (size_t)j * E * RK * H, nullptr,
                                                nullptr, aup, nullptr, T, E * RK, H, 0);
            dim3 gf2(H / 64, T / 64);
            gemm_kernel<<<gf2, 256, 0, stream>>>(bh, fw2 + (size_t)i * H * FF, fb2 + i * H,
                                                 nullptr, bo, nullptr, T, H, FF, 0);
            gemm_kernel<<<ga, 256, 0, stream>>>(bh, lAd + (size_t)j * E * RK * FF, nullptr,
                                                nullptr, dn0, nullptr, T, E * RK, FF, 0);
            expert_kernel<<<T, 256, 0, stream>>>(bo, aup, dn0, Mbuf, wb,
                                                 lBd + (size_t)j * E * H * RK, res1, hs);
        }
    }
    ln_kernel<<<T, 256, 0, stream>>>(hs, flnw, flnb, (float*)d_out, 1e-12f);
}

// Round 3
// 3882.092 us; speedup vs baseline: 4.0576x; 4.0576x over previous
//
#include <hip/hip_runtime.h>
#include <math.h>

#define L 12
#define H 768
#define NH 12
#define DH 64
#define FF 3072
#define B 32
#define R 29
#define D 14
#define E 15
#define RK 8
#define S 30
#define H2 384
#define T (B*S)
#define SCALING 2.0f

typedef __bf16 bf16x8 __attribute__((ext_vector_type(8)));
typedef float f32x4 __attribute__((ext_vector_type(4)));

__device__ __forceinline__ float gelu_f(float x) {
    return 0.5f * x * (1.0f + erff(x * 0.70710678118654752f));
}

// fp32 -> bf16 (round to nearest even)
__device__ __forceinline__ unsigned short f2b(float f) {
    union { float f; unsigned int u; } v; v.f = f;
    unsigned int r = v.u + 0x7FFFu + ((v.u >> 16) & 1u);
    return (unsigned short)(r >> 16);
}
__device__ __forceinline__ float b2f(unsigned short h) {
    union { unsigned int u; float f; } v; v.u = ((unsigned int)h) << 16;
    return v.f;
}
// split x into hi+lo bf16
__device__ __forceinline__ void split2(float x, unsigned short& hi, unsigned short& lo) {
    hi = f2b(x);
    lo = f2b(x - b2f(hi));
}

// block reduce over 256 threads (4 waves of 64)
__device__ __forceinline__ float block_sum256(float v, float* red) {
    int tid = threadIdx.x;
    #pragma unroll
    for (int off = 32; off > 0; off >>= 1) v += __shfl_down(v, off, 64);
    if ((tid & 63) == 0) red[tid >> 6] = v;
    __syncthreads();
    float s = red[0] + red[1] + red[2] + red[3];
    __syncthreads();
    return s;
}

__global__ void init_hs(const float* __restrict__ region, const float* __restrict__ cls,
                        float* __restrict__ hs) {
    int idx = blockIdx.x * blockDim.x + threadIdx.x;
    if (idx >= T * H) return;
    int h = idx % H;
    int t = idx / H;
    int s = t % S;
    int b = t / S;
    hs[idx] = (s == 0) ? cls[h] : region[((size_t)b * R + (s - 1)) * H + h];
}

// fused per-layer weight conversion fp32 -> bf16 hi/lo (up to 6 segments)
struct CvtArgs {
    const float* s[6];
    unsigned short* dh[6];
    unsigned short* dl[6];
    int n4[6];   // length/4 per segment
    int nseg;
};
__global__ __launch_bounds__(256) void cvt_kernel(CvtArgs a, int total4) {
    int i = blockIdx.x * 256 + threadIdx.x;
    if (i >= total4) return;
    int seg = 0;
    int off = i;
    while (seg < a.nseg && off >= a.n4[seg]) { off -= a.n4[seg]; seg++; }
    const float4 src = ((const float4*)a.s[seg])[off];
    ushort4 oh, ol;
    split2(src.x, oh.x, ol.x);
    split2(src.y, oh.y, ol.y);
    split2(src.z, oh.z, ol.z);
    split2(src.w, oh.w, ol.w);
    ((ushort4*)a.dh[seg])[off] = oh;
    ((ushort4*)a.dl[seg])[off] = ol;
}

// LayerNorm: one block per token; optional fp32 out and bf16 hi/lo out
__global__ __launch_bounds__(256) void ln_kernel(const float* __restrict__ x,
                                                 const float* __restrict__ w,
                                                 const float* __restrict__ b,
                                                 float* __restrict__ outf,
                                                 unsigned short* __restrict__ outh,
                                                 unsigned short* __restrict__ outl,
                                                 float eps) {
    __shared__ float red[4];
    int t = blockIdx.x;
    const float* xp = x + (size_t)t * H;
    float vals[3];
    float lsum = 0.f;
    #pragma unroll
    for (int i = 0; i < 3; i++) { vals[i] = xp[threadIdx.x + i * 256]; lsum += vals[i]; }
    float mean = block_sum256(lsum, red) * (1.0f / H);
    float lsq = 0.f;
    #pragma unroll
    for (int i = 0; i < 3; i++) { float d = vals[i] - mean; lsq += d * d; }
    float var = block_sum256(lsq, red) * (1.0f / H);
    float rstd = rsqrtf(var + eps);
    #pragma unroll
    for (int i = 0; i < 3; i++) {
        int h = threadIdx.x + i * 256;
        float v = (vals[i] - mean) * rstd * w[h] + b[h];
        if (outf) outf[(size_t)t * H + h] = v;
        if (outh) {
            unsigned short hi, lo;
            split2(v, hi, lo);
            outh[(size_t)t * H + h] = hi;
            outl[(size_t)t * H + h] = lo;
        }
    }
}

// bf16 hi/lo split MFMA GEMM (pseudo-fp32):
// C[m,n] = act(sum_k A[m,k]*W[n,k] + bias[n]),  A = Ah+Al, W = Wh+Wl
// acc += Ah*Wh + Ah*Wl + Al*Wh
#define PADC 68
__global__ __launch_bounds__(256) void gemm_mfma(
    const unsigned short* __restrict__ Ah, const unsigned short* __restrict__ Al,
    const unsigned short* __restrict__ Wh, const unsigned short* __restrict__ Wl,
    const float* __restrict__ bias, const float* __restrict__ resid,
    float* __restrict__ Cf, unsigned short* __restrict__ Cbh,
    unsigned short* __restrict__ Cbl, float* __restrict__ Cres,
    int M, int N, int K, int act)
{
    __shared__ unsigned short Ash[8 * PADC * 8];
    __shared__ unsigned short Asl[8 * PADC * 8];
    __shared__ unsigned short Wsh[8 * PADC * 8];
    __shared__ unsigned short Wsl[8 * PADC * 8];
    int tid = threadIdx.x;
    int lane = tid & 63;
    int wave = tid >> 6;
    int wr = wave >> 1, wc = wave & 1;
    int l15 = lane & 15, l4 = lane >> 4;
    int m0 = blockIdx.y * 64, n0 = blockIdx.x * 64;
    int g = tid & 3, row = tid >> 2;

    f32x4 acc[2][2];
    #pragma unroll
    for (int i = 0; i < 2; i++)
        #pragma unroll
        for (int j = 0; j < 2; j++) acc[i][j] = (f32x4){0.f, 0.f, 0.f, 0.f};

    const unsigned short* Ahp = Ah + (size_t)(m0 + row) * K + g * 16;
    const unsigned short* Alp = Al + (size_t)(m0 + row) * K + g * 16;
    int nrow = n0 + row;
    bool wok = nrow < N;
    const unsigned short* Whp = Wh + (size_t)(wok ? nrow : 0) * K + g * 16;
    const unsigned short* Wlp = Wl + (size_t)(wok ? nrow : 0) * K + g * 16;

    for (int k0 = 0; k0 < K; k0 += 64) {
        uint4 ah0 = *(const uint4*)(Ahp + k0);
        uint4 ah1 = *(const uint4*)(Ahp + k0 + 8);
        uint4 al0 = *(const uint4*)(Alp + k0);
        uint4 al1 = *(const uint4*)(Alp + k0 + 8);
        uint4 wh0 = make_uint4(0,0,0,0), wh1 = make_uint4(0,0,0,0);
        uint4 wl0 = make_uint4(0,0,0,0), wl1 = make_uint4(0,0,0,0);
        if (wok) {
            wh0 = *(const uint4*)(Whp + k0);
            wh1 = *(const uint4*)(Whp + k0 + 8);
            wl0 = *(const uint4*)(Wlp + k0);
            wl1 = *(const uint4*)(Wlp + k0 + 8);
        }
        __syncthreads();
        *(uint4*)&Ash[((2 * g) * PADC + row) * 8] = ah0;
        *(uint4*)&Ash[((2 * g + 1) * PADC + row) * 8] = ah1;
        *(uint4*)&Asl[((2 * g) * PADC + row) * 8] = al0;
        *(uint4*)&Asl[((2 * g + 1) * PADC + row) * 8] = al1;
        *(uint4*)&Wsh[((2 * g) * PADC + row) * 8] = wh0;
        *(uint4*)&Wsh[((2 * g + 1) * PADC + row) * 8] = wh1;
        *(uint4*)&Wsl[((2 * g) * PADC + row) * 8] = wl0;
        *(uint4*)&Wsl[((2 * g + 1) * PADC + row) * 8] = wl1;
        __syncthreads();
        #pragma unroll
        for (int ks = 0; ks < 2; ks++) {
            int kc = ks * 4 + l4;
            int aoff0 = (kc * PADC + wr * 32 + l15) * 8;
            int aoff1 = (kc * PADC + wr * 32 + 16 + l15) * 8;
            int woff0 = (kc * PADC + wc * 32 + l15) * 8;
            int woff1 = (kc * PADC + wc * 32 + 16 + l15) * 8;
            bf16x8 ah_0 = *(const bf16x8*)&Ash[aoff0];
            bf16x8 ah_1 = *(const bf16x8*)&Ash[aoff1];
            bf16x8 al_0 = *(const bf16x8*)&Asl[aoff0];
            bf16x8 al_1 = *(const bf16x8*)&Asl[aoff1];
            bf16x8 wh_0 = *(const bf16x8*)&Wsh[woff0];
            bf16x8 wh_1 = *(const bf16x8*)&Wsh[woff1];
            bf16x8 wl_0 = *(const bf16x8*)&Wsl[woff0];
            bf16x8 wl_1 = *(const bf16x8*)&Wsl[woff1];
            // hi*hi
            acc[0][0] = __builtin_amdgcn_mfma_f32_16x16x32_bf16(ah_0, wh_0, acc[0][0], 0, 0, 0);
            acc[0][1] = __builtin_amdgcn_mfma_f32_16x16x32_bf16(ah_0, wh_1, acc[0][1], 0, 0, 0);
            acc[1][0] = __builtin_amdgcn_mfma_f32_16x16x32_bf16(ah_1, wh_0, acc[1][0], 0, 0, 0);
            acc[1][1] = __builtin_amdgcn_mfma_f32_16x16x32_bf16(ah_1, wh_1, acc[1][1], 0, 0, 0);
            // hi*lo
            acc[0][0] = __builtin_amdgcn_mfma_f32_16x16x32_bf16(ah_0, wl_0, acc[0][0], 0, 0, 0);
            acc[0][1] = __builtin_amdgcn_mfma_f32_16x16x32_bf16(ah_0, wl_1, acc[0][1], 0, 0, 0);
            acc[1][0] = __builtin_amdgcn_mfma_f32_16x16x32_bf16(ah_1, wl_0, acc[1][0], 0, 0, 0);
            acc[1][1] = __builtin_amdgcn_mfma_f32_16x16x32_bf16(ah_1, wl_1, acc[1][1], 0, 0, 0);
            // lo*hi
            acc[0][0] = __builtin_amdgcn_mfma_f32_16x16x32_bf16(al_0, wh_0, acc[0][0], 0, 0, 0);
            acc[0][1] = __builtin_amdgcn_mfma_f32_16x16x32_bf16(al_0, wh_1, acc[0][1], 0, 0, 0);
            acc[1][0] = __builtin_amdgcn_mfma_f32_16x16x32_bf16(al_1, wh_0, acc[1][0], 0, 0, 0);
            acc[1][1] = __builtin_amdgcn_mfma_f32_16x16x32_bf16(al_1, wh_1, acc[1][1], 0, 0, 0);
        }
    }
    #pragma unroll
    for (int ti = 0; ti < 2; ti++) {
        #pragma unroll
        for (int tj = 0; tj < 2; tj++) {
            int n = n0 + wc * 32 + tj * 16 + l15;
            if (n >= N) continue;
            float bv = bias ? bias[n] : 0.f;
            #pragma unroll
            for (int r = 0; r < 4; r++) {
                int m = m0 + wr * 32 + ti * 16 + l4 * 4 + r;
                float v = acc[ti][tj][r] + bv;
                if (act) v = gelu_f(v);
                size_t o = (size_t)m * N + n;
                if (Cf) Cf[o] = v;
                if (Cbh) {
                    unsigned short hi, lo;
                    split2(v, hi, lo);
                    Cbh[o] = hi;
                    Cbl[o] = lo;
                }
                if (Cres) Cres[o] = v + resid[o];
            }
        }
    }
}

// fused attention: one block per (b, head); qkv fp32 (token, 3H); ctx out bf16 hi/lo
__global__ __launch_bounds__(256) void attn_kernel(const float* __restrict__ qkv,
                                                   unsigned short* __restrict__ ctxh,
                                                   unsigned short* __restrict__ ctxl) {
    int b = blockIdx.x / NH, nh = blockIdx.x % NH;
    __shared__ float qs[S * DH], ks[S * DH], vs[S * DH];
    __shared__ float sc[S][S + 1];
    int tid = threadIdx.x;
    for (int e = tid; e < S * DH; e += 256) {
        int s = e / DH, d = e % DH;
        size_t base = (size_t)(b * S + s) * (3 * H) + nh * DH + d;
        qs[e] = qkv[base];
        ks[e] = qkv[base + H];
        vs[e] = qkv[base + 2 * H];
    }
    __syncthreads();
    for (int e = tid; e < S * S; e += 256) {
        int qi = e / S, kj = e % S;
        float acc = 0.f;
        #pragma unroll
        for (int d = 0; d < DH; d++) acc += qs[qi * DH + d] * ks[kj * DH + d];
        sc[qi][kj] = acc * 0.125f;
    }
    __syncthreads();
    if (tid < S) {
        float mx = -1e30f;
        for (int k = 0; k < S; k++) mx = fmaxf(mx, sc[tid][k]);
        float sum = 0.f;
        for (int k = 0; k < S; k++) { float ex = __expf(sc[tid][k] - mx); sc[tid][k] = ex; sum += ex; }
        float inv = 1.0f / sum;
        for (int k = 0; k < S; k++) sc[tid][k] *= inv;
    }
    __syncthreads();
    for (int e = tid; e < S * DH; e += 256) {
        int s = e / DH, d = e % DH;
        float acc = 0.f;
        for (int k = 0; k < S; k++) acc += sc[s][k] * vs[k * DH + d];
        unsigned short hi, lo;
        split2(acc, hi, lo);
        size_t o = (size_t)(b * S + s) * H + nh * DH + d;
        ctxh[o] = hi;
        ctxl[o] = lo;
    }
}

// pooled[b,d,h] = sum_r attn_out[b,1+r,h]*mask[r,d] / max(cnt[d],1)
__global__ __launch_bounds__(256) void pool_kernel(const float* __restrict__ attn_out,
                                                   const float* __restrict__ mask,
                                                   float* __restrict__ pooled) {
    int b = blockIdx.x / D, d = blockIdx.x % D;
    float cnt = 0.f;
    for (int r = 0; r < R; r++) cnt += mask[r * D + d];
    float inv = 1.0f / fmaxf(cnt, 1.0f);
    for (int h = threadIdx.x; h < H; h += 256) {
        float acc = 0.f;
        for (int r = 0; r < R; r++) {
            float mv = mask[r * D + d];
            if (mv != 0.f) acc += attn_out[(size_t)(b * S + 1 + r) * H + h] * mv;
        }
        pooled[(size_t)(b * D + d) * H + h] = acc * inv;
    }
}

// cls head: block per (b,d) -> active_dis[b,d] in {0,1}
__global__ __launch_bounds__(256) void cls_kernel(
    const float* __restrict__ pooled, const float* __restrict__ w1,
    const float* __restrict__ b1, const float* __restrict__ lnw,
    const float* __restrict__ lnb, const float* __restrict__ w2,
    const float* __restrict__ b2, const float* __restrict__ mask,
    float* __restrict__ act_dis)
{
    int b = blockIdx.x / D, d = blockIdx.x % D;
    __shared__ float h1[H2];
    __shared__ float red[4];
    const float* pp = pooled + (size_t)(b * D + d) * H;
    for (int k = threadIdx.x; k < H2; k += 256) {
        const float* wp = w1 + ((size_t)d * H2 + k) * H;
        float acc = 0.f;
        for (int h = 0; h < H; h++) acc += pp[h] * wp[h];
        h1[k] = acc + b1[d * H2 + k];
    }
    __syncthreads();
    float ls = 0.f;
    for (int k = threadIdx.x; k < H2; k += 256) ls += h1[k];
    float mean = block_sum256(ls, red) * (1.0f / H2);
    float lq = 0.f;
    for (int k = threadIdx.x; k < H2; k += 256) { float dv = h1[k] - mean; lq += dv * dv; }
    float var = block_sum256(lq, red) * (1.0f / H2);
    float rstd = rsqrtf(var + 1e-5f);
    float lp = 0.f;
    for (int k = threadIdx.x; k < H2; k += 256) {
        float g = gelu_f((h1[k] - mean) * rstd * lnw[d * H2 + k] + lnb[d * H2 + k]);
        lp += g * w2[d * H2 + k];
    }
    float pred = block_sum256(lp, red) + b2[d];
    if (threadIdx.x == 0) {
        float cnt = 0.f;
        for (int r = 0; r < R; r++) cnt += mask[r * D + d];
        act_dis[b * D + d] = (cnt > 0.f && pred > 0.f) ? 1.0f : 0.0f;
    }
}

// expert mixture weights w[b,s,e]
__global__ void w_kernel(const float* __restrict__ act_dis, const float* __restrict__ mask,
                         float* __restrict__ wbuf) {
    int t = blockIdx.x * blockDim.x + threadIdx.x;
    if (t >= T) return;
    int b = t / S, s = t % S;
    float a[E];
    float sum = 0.f;
    for (int d = 0; d < D; d++) {
        float v = 0.f;
        if (s > 0 && mask[(s - 1) * D + d] > 0.f) v = act_dis[b * D + d];
        a[d] = v; sum += v;
    }
    a[D] = 1.0f; sum += 1.0f;
    float inv = 1.0f / fmaxf(sum, 1.0f);
    for (int e = 0; e < E; e++) wbuf[t * E + e] = a[e] * inv;
}

// M[e,r,r2] = sum_f B_up[e,f,r2] * A_down[e,r,f]
__global__ __launch_bounds__(256) void m_kernel(const float* __restrict__ Bup,
                                                const float* __restrict__ Adn,
                                                float* __restrict__ Mbuf) {
    __shared__ float red[4];
    int id = blockIdx.x;
    int e = id / (RK * RK);
    int r = (id / RK) % RK;
    int r2 = id % RK;
    float acc = 0.f;
    for (int f = threadIdx.x; f < FF; f += 256)
        acc += Bup[((size_t)e * FF + f) * RK + r2] * Adn[((size_t)e * RK + r) * FF + f];
    float s = block_sum256(acc, red);
    if (threadIdx.x == 0) Mbuf[id] = s;
}

// per-token expert combine
__global__ __launch_bounds__(256) void expert_kernel(
    const float* __restrict__ base_out, const float* __restrict__ aup,
    const float* __restrict__ dn0, const float* __restrict__ Mbuf,
    const float* __restrict__ wbuf, const float* __restrict__ Bdn,
    const float* __restrict__ res1, float* __restrict__ hs)
{
    int t = blockIdx.x;
    __shared__ float bo[H], vtmp[H], fin[H];
    __shared__ float Ms[E * RK * RK];
    __shared__ float aups[E * RK], dn0s[E * RK], adn[RK], ws_[E];
    __shared__ float red[4];
    int tid = threadIdx.x;
    for (int h = tid; h < H; h += 256) { bo[h] = base_out[(size_t)t * H + h]; fin[h] = 0.f; }
    for (int i = tid; i < E * RK * RK; i += 256) Ms[i] = Mbuf[i];
    for (int i = tid; i < E * RK; i += 256) {
        aups[i] = aup[(size_t)t * E * RK + i];
        dn0s[i] = dn0[(size_t)t * E * RK + i];
    }
    if (tid < E) ws_[tid] = wbuf[t * E + tid];
    __syncthreads();
    for (int e = 0; e < E; e++) {
        float we = ws_[e];
        if (we == 0.f) continue;
        if (tid < RK) {
            float acc = dn0s[e * RK + tid];
            #pragma unroll
            for (int r2 = 0; r2 < RK; r2++)
                acc += SCALING * aups[e * RK + r2] * Ms[(e * RK + tid) * RK + r2];
            adn[tid] = acc;
        }
        __syncthreads();
        float lsum = 0.f;
        for (int h = tid; h < H; h += 256) {
            const float* bp = Bdn + ((size_t)e * H + h) * RK;
            float ld = 0.f;
            #pragma unroll
            for (int r = 0; r < RK; r++) ld += adn[r] * bp[r];
            float v = bo[h] + SCALING * ld;
            vtmp[h] = v;
            lsum += v;
        }
        float mean = block_sum256(lsum, red) * (1.0f / H);
        float lq = 0.f;
        for (int h = tid; h < H; h += 256) { float dv = vtmp[h] - mean; lq += dv * dv; }
        float var = block_sum256(lq, red) * (1.0f / H);
        float rstd = rsqrtf(var + 1e-5f);
        for (int h = tid; h < H; h += 256) fin[h] += we * (vtmp[h] - mean) * rstd;
        __syncthreads();
    }
    for (int h = tid; h < H; h += 256)
        hs[(size_t)t * H + h] = fin[h] + res1[(size_t)t * H + h];
}

extern "C" void kernel_launch(void* const* d_in, const int* in_sizes, int n_in,
                              void* d_out, int out_size, void* d_ws, size_t ws_size,
                              hipStream_t stream) {
    (void)in_sizes; (void)n_in; (void)out_size; (void)ws_size;
    const float* region = (const float*)d_in[0];
    const float* mask   = (const float*)d_in[1];
    const float* cls    = (const float*)d_in[2];
    const float* ln1w   = (const float*)d_in[3];
    const float* ln1b   = (const float*)d_in[4];
    const float* qkvw   = (const float*)d_in[5];
    const float* qkvb   = (const float*)d_in[6];
    const float* aow    = (const float*)d_in[7];
    const float* aob    = (const float*)d_in[8];
    const float* ln2w   = (const float*)d_in[9];
    const float* ln2b   = (const float*)d_in[10];
    const float* fw1    = (const float*)d_in[11];
    const float* fb1    = (const float*)d_in[12];
    const float* fw2    = (const float*)d_in[13];
    const float* fb2    = (const float*)d_in[14];
    const float* cw1    = (const float*)d_in[15];
    const float* cb1    = (const float*)d_in[16];
    const float* clnw   = (const float*)d_in[17];
    const float* clnb   = (const float*)d_in[18];
    const float* cw2    = (const float*)d_in[19];
    const float* cb2    = (const float*)d_in[20];
    const float* lAu    = (const float*)d_in[21];
    const float* lBu    = (const float*)d_in[22];
    const float* lAd    = (const float*)d_in[23];
    const float* lBd    = (const float*)d_in[24];
    const float* flnw   = (const float*)d_in[25];
    const float* flnb   = (const float*)d_in[26];

    // fp32 workspace
    float* p = (float*)d_ws;
    float* hs   = p; p += (size_t)T * H;
    float* qkv  = p; p += (size_t)T * 3 * H;
    float* aout = p; p += (size_t)T * H;
    float* res1 = p; p += (size_t)T * H;
    float* bo   = p; p += (size_t)T * H;
    float* aup  = p; p += (size_t)T * E * RK;
    float* dn0  = p; p += (size_t)T * E * RK;
    float* Mbuf = p; p += E * RK * RK;
    float* adis = p; p += B * D;
    float* wb   = p; p += (size_t)T * E;
    float* pooled = p; p += (size_t)B * D * H;
    // bf16 workspace (hi/lo pairs)
    unsigned short* q = (unsigned short*)p;
    unsigned short* xln_h  = q; q += (size_t)T * H;
    unsigned short* xln_l  = q; q += (size_t)T * H;
    unsigned short* y_h    = q; q += (size_t)T * H;
    unsigned short* y_l    = q; q += (size_t)T * H;
    unsigned short* ctx_h  = q; q += (size_t)T * H;
    unsigned short* ctx_l  = q; q += (size_t)T * H;
    unsigned short* bh_h   = q; q += (size_t)T * FF;
    unsigned short* bh_l   = q; q += (size_t)T * FF;
    unsigned short* qkvw_h = q; q += (size_t)3 * H * H;
    unsigned short* qkvw_l = q; q += (size_t)3 * H * H;
    unsigned short* aow_h  = q; q += (size_t)H * H;
    unsigned short* aow_l  = q; q += (size_t)H * H;
    unsigned short* fw1_h  = q; q += (size_t)FF * H;
    unsigned short* fw1_l  = q; q += (size_t)FF * H;
    unsigned short* fw2_h  = q; q += (size_t)FF * H;
    unsigned short* fw2_l  = q; q += (size_t)FF * H;
    unsigned short* lAu_h  = q; q += (size_t)E * RK * H;
    unsigned short* lAu_l  = q; q += (size_t)E * RK * H;
    unsigned short* lAd_h  = q; q += (size_t)E * RK * FF;
    unsigned short* lAd_l  = q; q += (size_t)E * RK * FF;

    init_hs<<<(T * H + 255) / 256, 256, 0, stream>>>(region, cls, hs);

    for (int i = 0; i < L; i++) {
        int j = i / 2;
        CvtArgs ca;
        ca.s[0] = qkvw + (size_t)i * 3 * H * H; ca.dh[0] = qkvw_h; ca.dl[0] = qkvw_l; ca.n4[0] = 3 * H * H / 4;
        ca.s[1] = aow  + (size_t)i * H * H;     ca.dh[1] = aow_h;  ca.dl[1] = aow_l;  ca.n4[1] = H * H / 4;
        ca.s[2] = fw1  + (size_t)i * FF * H;    ca.dh[2] = fw1_h;  ca.dl[2] = fw1_l;  ca.n4[2] = FF * H / 4;
        ca.s[3] = fw2  + (size_t)i * FF * H;    ca.dh[3] = fw2_h;  ca.dl[3] = fw2_l;  ca.n4[3] = FF * H / 4;
        ca.nseg = 4;
        int total4 = ca.n4[0] + ca.n4[1] + ca.n4[2] + ca.n4[3];
        if (i % 2 == 0) {
            ca.s[4] = lAu + (size_t)j * E * RK * H;  ca.dh[4] = lAu_h; ca.dl[4] = lAu_l; ca.n4[4] = E * RK * H / 4;
            ca.s[5] = lAd + (size_t)j * E * RK * FF; ca.dh[5] = lAd_h; ca.dl[5] = lAd_l; ca.n4[5] = E * RK * FF / 4;
            ca.nseg = 6;
            total4 += ca.n4[4] + ca.n4[5];
        }
        cvt_kernel<<<(total4 + 255) / 256, 256, 0, stream>>>(ca, total4);

        ln_kernel<<<T, 256, 0, stream>>>(hs, ln1w + i * H, ln1b + i * H,
                                         nullptr, xln_h, xln_l, 1e-12f);
        dim3 g1(3 * H / 64, T / 64);
        gemm_mfma<<<g1, 256, 0, stream>>>(xln_h, xln_l, qkvw_h, qkvw_l,
                                          qkvb + i * 3 * H, nullptr,
                                          qkv, nullptr, nullptr, nullptr, T, 3 * H, H, 0);
        attn_kernel<<<B * NH, 256, 0, stream>>>(qkv, ctx_h, ctx_l);
        dim3 g2(H / 64, T / 64);
        gemm_mfma<<<g2, 256, 0, stream>>>(ctx_h, ctx_l, aow_h, aow_l,
                                          aob + i * H, hs,
                                          aout, nullptr, nullptr, res1, T, H, H, 0);
        ln_kernel<<<T, 256, 0, stream>>>(res1, ln2w + i * H, ln2b + i * H,
                                         nullptr, y_h, y_l, 1e-12f);
        dim3 gf1(FF / 64, T / 64);
        gemm_mfma<<<gf1, 256, 0, stream>>>(y_h, y_l, fw1_h, fw1_l,
                                           fb1 + i * FF, nullptr,
                                           nullptr, bh_h, bh_l, nullptr, T, FF, H, 1);
        if (i % 2 == 1) {
            dim3 gf2(H / 64, T / 64);
            gemm_mfma<<<gf2, 256, 0, stream>>>(bh_h, bh_l, fw2_h, fw2_l,
                                               fb2 + i * H, res1,
                                               nullptr, nullptr, nullptr, hs, T, H, FF, 0);
        } else {
            pool_kernel<<<B * D, 256, 0, stream>>>(aout, mask, pooled);
            cls_kernel<<<B * D, 256, 0, stream>>>(pooled, cw1 + (size_t)j * D * H2 * H,
                cb1 + (size_t)j * D * H2, clnw + (size_t)j * D * H2, clnb + (size_t)j * D * H2,
                cw2 + (size_t)j * D * H2, cb2 + (size_t)j * D, mask, adis);
            w_kernel<<<(T + 255) / 256, 256, 0, stream>>>(adis, mask, wb);
            m_kernel<<<E * RK * RK, 256, 0, stream>>>(lBu + (size_t)j * E * FF * RK,
                                                      lAd + (size_t)j * E * RK * FF, Mbuf);
            dim3 ga((E * RK + 63) / 64, T / 64);
            gemm_mfma<<<ga, 256, 0, stream>>>(y_h, y_l, lAu_h, lAu_l,
                                              nullptr, nullptr,
                                              aup, nullptr, nullptr, nullptr, T, E * RK, H, 0);
            dim3 gf2(H / 64, T / 64);
            gemm_mfma<<<gf2, 256, 0, stream>>>(bh_h, bh_l, fw2_h, fw2_l,
                                               fb2 + i * H, nullptr,
                                               bo, nullptr, nullptr, nullptr, T, H, FF, 0);
            gemm_mfma<<<ga, 256, 0, stream>>>(bh_h, bh_l, lAd_h, lAd_l,
                                              nullptr, nullptr,
                                              dn0, nullptr, nullptr, nullptr, T, E * RK, FF, 0);
            expert_kernel<<<T, 256, 0, stream>>>(bo, aup, dn0, Mbuf, wb,
                                                 lBd + (size_t)j * E * H * RK, res1, hs);
        }
    }
    ln_kernel<<<T, 256, 0, stream>>>(hs, flnw, flnb, (float*)d_out, nullptr, nullptr, 1e-12f);
}